// Round 5
// baseline (852.463 us; speedup 1.0000x reference)
//
#include <hip/hip_runtime.h>
#include <math.h>

#define N_NODES 200000
#define N_HE    100000
#define NNZ     1000000
#define F_RAW   29
#define N_MACRO 512
#define SLOPE   0.1f
#define L_TOTAL (N_NODES + N_HE)   // 300000 combined counters
#define NB_SCAN 293                // ceil(300000/1024)

__device__ __forceinline__ float lrelu(float v) { return v >= 0.f ? v : SLOPE * v; }
__device__ __forceinline__ float bf2f(unsigned short u) { return __uint_as_float(((unsigned)u) << 16); }
__device__ __forceinline__ unsigned short f2bf(float f) {
    unsigned u = __float_as_uint(f);
    unsigned r = u + 0x7FFFu + ((u >> 16) & 1u);   // RNE
    return (unsigned short)(r >> 16);
}

// ---------- fills ----------
__global__ __launch_bounds__(256) void fill_f32(float* p, long long n, float v) {
    long long i = (long long)blockIdx.x * blockDim.x + threadIdx.x;
    long long st = (long long)gridDim.x * blockDim.x;
    for (; i < n; i += st) p[i] = v;
}

__global__ __launch_bounds__(256) void k_ismacro(const int* __restrict__ mi,
                                                 float* __restrict__ ismacro, int* __restrict__ mcount) {
    int i = blockIdx.x * blockDim.x + threadIdx.x;
    if (i < N_MACRO) {
        ismacro[mi[i]] = 1.0f;
        atomicAdd(&mcount[mi[i]], 1);
    }
}

// ---------- va[k] = W1[k,:]·att[:64], va[32] = b1·att[:64] ----------
__global__ __launch_bounds__(64) void k_va(const float* __restrict__ W1, const float* __restrict__ b1,
                                           const float* __restrict__ att, float* __restrict__ va) {
    int t = threadIdx.x;
    if (t < 32) {
        float a = 0.f;
        for (int c = 0; c < 64; c++) a += W1[t * 64 + c] * att[c];
        va[t] = a;
    } else if (t == 32) {
        float a = 0.f;
        for (int c = 0; c < 64; c++) a += b1[c] * att[c];
        va[32] = a;
    }
}

// ---------- build h rows (32 floats) + xn_att ----------
__global__ __launch_bounds__(256) void k_h(
    const float* __restrict__ x, const float* __restrict__ fp,
    const float* __restrict__ ismacro, const float* __restrict__ va,
    float* __restrict__ h, float* __restrict__ xn_att)
{
    const int lane = threadIdx.x & 63;
    const int half = lane >> 5, k = lane & 31;
    int wid = (blockIdx.x * blockDim.x + threadIdx.x) >> 6;
    int nw = (gridDim.x * blockDim.x) >> 6;
    float vak = va[k];
    float c0 = va[32];
    for (int base = wid * 2; base < N_NODES; base += nw * 2) {
        int n = base + half;
        float v;
        if (k < 29)       v = x[(size_t)n * F_RAW + k];
        else if (k == 29) v = fp[2 * n];
        else if (k == 30) v = fp[2 * n + 1];
        else              v = ismacro[n];
        h[(size_t)n * 32 + k] = v;
        float r = v * vak;
        #pragma unroll
        for (int o = 16; o > 0; o >>= 1) r += __shfl_xor(r, o, 32);
        if (k == 0) xn_att[n] = r + c0;
    }
}

// ---------- counts + per-he pinf sums ----------
__global__ __launch_bounds__(256) void k_count(
    const int* __restrict__ nidx, const int* __restrict__ hidx,
    const float* __restrict__ pinf, int* __restrict__ cnt, float* __restrict__ pfsum)
{
    int i = blockIdx.x * blockDim.x + threadIdx.x;
    int st = gridDim.x * blockDim.x;
    const float4* pf4 = (const float4*)pinf;
    for (int p = i; p < NNZ; p += st) {
        int n = nidx[p], e = hidx[p];
        atomicAdd(&cnt[n], 1);
        atomicAdd(&cnt[N_NODES + e], 1);
        float4 q = pf4[p];
        atomicAdd(&pfsum[e * 4 + 0], q.x);
        atomicAdd(&pfsum[e * 4 + 1], q.y);
        atomicAdd(&pfsum[e * 4 + 2], q.z);
        atomicAdd(&pfsum[e * 4 + 3], q.w);
    }
}

// ---------- scan of cnt (length L_TOTAL) -> row_ptr ----------
__global__ __launch_bounds__(256) void k_scan1(const int* __restrict__ cnt,
                                               int* __restrict__ row_ptr, int* __restrict__ partials)
{
    __shared__ int sA[256], sB[256];
    const int t = threadIdx.x;
    const int base = blockIdx.x * 1024 + t * 4;
    int v0 = base + 0 < L_TOTAL ? cnt[base + 0] : 0;
    int v1 = base + 1 < L_TOTAL ? cnt[base + 1] : 0;
    int v2 = base + 2 < L_TOTAL ? cnt[base + 2] : 0;
    int v3 = base + 3 < L_TOTAL ? cnt[base + 3] : 0;
    sA[t] = v0 + v1 + v2 + v3;
    __syncthreads();
    int* src = sA; int* dst = sB;
    for (int off = 1; off < 256; off <<= 1) {
        int v = src[t];
        if (t >= off) v += src[t - off];
        dst[t] = v;
        __syncthreads();
        int* tmp = src; src = dst; dst = tmp;
    }
    int excl = t > 0 ? src[t - 1] : 0;
    if (base + 0 < L_TOTAL) row_ptr[base + 0] = excl;
    if (base + 1 < L_TOTAL) row_ptr[base + 1] = excl + v0;
    if (base + 2 < L_TOTAL) row_ptr[base + 2] = excl + v0 + v1;
    if (base + 3 < L_TOTAL) row_ptr[base + 3] = excl + v0 + v1 + v2;
    if (t == 255) partials[blockIdx.x] = src[255];
}

__global__ __launch_bounds__(512) void k_scan2(int* __restrict__ partials)
{
    __shared__ int sA[512], sB[512];
    const int t = threadIdx.x;
    sA[t] = t < NB_SCAN ? partials[t] : 0;
    __syncthreads();
    int* src = sA; int* dst = sB;
    for (int off = 1; off < 512; off <<= 1) {
        int v = src[t];
        if (t >= off) v += src[t - off];
        dst[t] = v;
        __syncthreads();
        int* tmp = src; src = dst; dst = tmp;
    }
    if (t < NB_SCAN) partials[t] = t > 0 ? src[t - 1] : 0;
    if (t == 0) partials[NB_SCAN] = src[511];
}

__global__ __launch_bounds__(256) void k_scan3(int* __restrict__ row_ptr, const int* __restrict__ partials)
{
    const int base = blockIdx.x * 1024 + threadIdx.x * 4;
    int add = partials[blockIdx.x];
    #pragma unroll
    for (int k = 0; k < 4; k++)
        if (base + k < L_TOTAL) row_ptr[base + k] += add;
    if (blockIdx.x == 0 && threadIdx.x == 0) row_ptr[L_TOTAL] = partials[NB_SCAN];
}

// ---------- scatter pins (node side: he id; he side: node id) ----------
__global__ __launch_bounds__(256) void k_scatter(
    const int* __restrict__ nidx, const int* __restrict__ hidx,
    const int* __restrict__ row_ptr, int* __restrict__ cnt, int* __restrict__ csr)
{
    int i = blockIdx.x * blockDim.x + threadIdx.x;
    int st = gridDim.x * blockDim.x;
    for (int p = i; p < NNZ; p += st) {
        int n = nidx[p], e = hidx[p];
        int pn = row_ptr[n] + atomicSub(&cnt[n], 1) - 1;
        csr[pn] = e;
        int pe = row_ptr[N_NODES + e] + atomicSub(&cnt[N_NODES + e], 1) - 1;
        csr[pe] = n;
    }
}

// ---------- he-side: gather h rows, matvec through W1, e_feat(bf16) + e_att ----------
__global__ __launch_bounds__(256) void k_he_agg(
    const int* __restrict__ row_ptr, const int* __restrict__ csr,
    const float* __restrict__ pfsum,
    const float* __restrict__ W1, const float* __restrict__ Wpin,
    const float* __restrict__ b1, const float* __restrict__ att,
    const float* __restrict__ h,
    unsigned short* __restrict__ e_feat, float* __restrict__ e_att)
{
    __shared__ float sW1[32 * 64];
    __shared__ float sWp[4 * 64];
    __shared__ float sb1[64];
    for (int i = threadIdx.x; i < 32 * 64; i += 256) sW1[i] = W1[i];
    if (threadIdx.x < 256) { }
    for (int i = threadIdx.x; i < 4 * 64; i += 256) sWp[i] = Wpin[i];
    if (threadIdx.x < 64) sb1[threadIdx.x] = b1[threadIdx.x];
    __syncthreads();
    const int lane = threadIdx.x & 63;
    const int half = lane >> 5, k32 = lane & 31;
    float att2 = att[64 + lane];
    int wid = (blockIdx.x * blockDim.x + threadIdx.x) >> 6;
    int nw = (gridDim.x * blockDim.x) >> 6;
    for (int e = wid; e < N_HE; e += nw) {
        int start = row_ptr[N_NODES + e];
        int deg = row_ptr[N_NODES + e + 1] - start;
        float hs = 0.f;
        for (int t0 = 0; t0 < deg; t0 += 8) {
            #pragma unroll
            for (int r = 0; r < 4; r++) {
                int t = t0 + 2 * r + half;
                int ok = t < deg;
                int n = ok ? csr[start + t] : 0;
                float v = ok ? h[(size_t)n * 32 + k32] : 0.f;
                hs += v;
            }
        }
        hs += __shfl_xor(hs, 32);
        float4 ps = ((const float4*)pfsum)[e];
        float acc = (float)deg * sb1[lane]
                  + ps.x * sWp[lane] + ps.y * sWp[64 + lane]
                  + ps.z * sWp[128 + lane] + ps.w * sWp[192 + lane];
        #pragma unroll
        for (int kk = 0; kk < 32; kk++) acc += __shfl(hs, kk) * sW1[kk * 64 + lane];
        float d = (float)(deg > 0 ? deg : 1);
        float v = acc / d;
        e_feat[(size_t)e * 64 + lane] = f2bf(v);
        float r = v * att2;
        #pragma unroll
        for (int o = 32; o > 0; o >>= 1) r += __shfl_down(r, o, 64);
        if (lane == 0) e_att[e] = r;
    }
}

// ---------- fused softmax+PNA + register-W GEMM + lrelu + pools ----------
// Wave w owns output channels [16w,16w+16); lane (kg=lane>>3, cg=lane&7) holds
// W[32kg..32kg+32)[2cg..2cg+1] in 64 VGPRs, loaded once. scat uses block-padded
// layout (36-word blocks) so the 8 kg-addresses hit 8 distinct bank groups.
__global__ __launch_bounds__(256, 4) void k_fused(
    const int* __restrict__ row_ptr, const int* __restrict__ csr,
    const float* __restrict__ xn_att, const float* __restrict__ e_att,
    const unsigned short* __restrict__ e_feat,
    const float* __restrict__ Wpost, const float* __restrict__ bpost,
    const int* __restrict__ mcount,
    float* __restrict__ sum_all, float* __restrict__ sum_mac)
{
    __shared__ __align__(16) float scat[32 * 288];   // 32 nodes x 8 blocks x 36 words
    const int lane = threadIdx.x & 63;
    const int wave = threadIdx.x >> 6;
    const int kg = lane >> 3;
    const int cg = lane & 7;
    // persistent W fragment: f = 32*kg + t, channels c0 = 16*wave + 2*cg, c0+1
    float2 wreg[32];
    {
        const float2* W2 = (const float2*)Wpost;
        #pragma unroll
        for (int t = 0; t < 32; t++)
            wreg[t] = W2[(size_t)(32 * kg + t) * 32 + wave * 8 + cg];
    }
    float2 bias = ((const float2*)bpost)[wave * 8 + cg];
    float2 pool = make_float2(0.f, 0.f), pmac = make_float2(0.f, 0.f);
    const int off_c = 36 * (lane >> 5) + (lane & 31);   // phase-A store offset for stat s: 72*s + off_c
    const int nbatches = N_NODES / 32;  // 6250
    for (int b = blockIdx.x; b < nbatches; b += gridDim.x) {
        const int base = b * 32;
        __syncthreads();
        // ---- phase A: 8 nodes per wave, single pass, unnormalized softmax-PNA ----
        for (int i = 0; i < 8; i++) {
            int j = wave * 8 + i;
            int n = base + j;
            int start = row_ptr[n];
            int deg = row_ptr[n + 1] - start;
            float xn = xn_att[n];
            float sw = 0.f, s = 0.f, sq = 0.f, mx = -INFINITY, mn = INFINITY;
            int t = 0;
            for (; t + 4 <= deg; t += 4) {
                int e0 = csr[start + t],     e1 = csr[start + t + 1];
                int e2 = csr[start + t + 2], e3 = csr[start + t + 3];
                float w0 = __expf(lrelu(xn + e_att[e0]));
                float w1 = __expf(lrelu(xn + e_att[e1]));
                float w2 = __expf(lrelu(xn + e_att[e2]));
                float w3 = __expf(lrelu(xn + e_att[e3]));
                float v0 = bf2f(e_feat[(size_t)e0 * 64 + lane]) * w0;
                float v1 = bf2f(e_feat[(size_t)e1 * 64 + lane]) * w1;
                float v2 = bf2f(e_feat[(size_t)e2 * 64 + lane]) * w2;
                float v3 = bf2f(e_feat[(size_t)e3 * 64 + lane]) * w3;
                sw += w0 + w1 + w2 + w3;
                s  += v0 + v1 + v2 + v3;
                sq += v0 * v0 + v1 * v1 + v2 * v2 + v3 * v3;
                mx = fmaxf(fmaxf(mx, v0), fmaxf(fmaxf(v1, v2), v3));
                mn = fminf(fminf(mn, v0), fminf(fminf(v1, v2), v3));
            }
            for (; t < deg; t++) {
                int e = csr[start + t];
                float w = __expf(lrelu(xn + e_att[e]));
                float v = bf2f(e_feat[(size_t)e * 64 + lane]) * w;
                sw += w; s += v; sq += v * v;
                mx = fmaxf(mx, v); mn = fminf(mn, v);
            }
            float invD = 1.f / (sw + 1e-16f);
            float dc = (float)(deg > 0 ? deg : 1);
            float mean = s * invD / dc;
            float sqm  = sq * invD * invD / dc;
            float stdv = sqrtf(fmaxf(sqm - mean * mean, 0.f) + 1e-12f);
            float* row = &scat[j * 288];
            row[off_c]       = mean;
            row[72 + off_c]  = deg > 0 ? mx * invD : 0.f;
            row[144 + off_c] = deg > 0 ? mn * invD : 0.f;
            row[216 + off_c] = stdv;
        }
        __syncthreads();
        // ---- phase B: all 32 nodes, W from registers, broadcast LDS reads ----
        for (int j = 0; j < 32; j++) {
            const float4* sc = (const float4*)&scat[j * 288 + kg * 36];
            float2 a = make_float2(0.f, 0.f);
            #pragma unroll
            for (int i = 0; i < 8; i++) {
                float4 c4 = sc[i];
                a.x += c4.x * wreg[4 * i + 0].x + c4.y * wreg[4 * i + 1].x
                     + c4.z * wreg[4 * i + 2].x + c4.w * wreg[4 * i + 3].x;
                a.y += c4.x * wreg[4 * i + 0].y + c4.y * wreg[4 * i + 1].y
                     + c4.z * wreg[4 * i + 2].y + c4.w * wreg[4 * i + 3].y;
            }
            a.x += __shfl_xor(a.x, 8);  a.y += __shfl_xor(a.y, 8);
            a.x += __shfl_xor(a.x, 16); a.y += __shfl_xor(a.y, 16);
            a.x += __shfl_xor(a.x, 32); a.y += __shfl_xor(a.y, 32);
            if (kg == 0) {
                float h0 = lrelu(a.x + bias.x);
                float h1 = lrelu(a.y + bias.y);
                float mc = (float)mcount[base + j];
                pool.x += h0; pool.y += h1;
                pmac.x += mc * h0; pmac.y += mc * h1;
            }
        }
    }
    if (kg == 0) {
        int c0 = wave * 16 + 2 * cg;
        atomicAdd(&sum_all[c0],     pool.x);
        atomicAdd(&sum_all[c0 + 1], pool.y);
        atomicAdd(&sum_mac[c0],     pmac.x);
        atomicAdd(&sum_mac[c0 + 1], pmac.y);
    }
}

// ---------- tiny MLP head ----------
__global__ __launch_bounds__(256) void k_final(
    const float* __restrict__ sum_all, const float* __restrict__ sum_mac,
    const float* __restrict__ Wm1, const float* __restrict__ bm1,
    const float* __restrict__ Wm2, const float* __restrict__ bm2,
    const float* __restrict__ Wm3, const float* __restrict__ bm3,
    float* __restrict__ out)
{
    __shared__ float spool[128];
    __shared__ float z1[64];
    __shared__ float z2[32];
    if (threadIdx.x < 64) {
        spool[threadIdx.x]      = sum_mac[threadIdx.x] / (float)N_MACRO;
        spool[64 + threadIdx.x] = sum_all[threadIdx.x] / (float)N_NODES;
    }
    __syncthreads();
    if (threadIdx.x < 64) {
        int j = threadIdx.x;
        float a = bm1[j];
        #pragma unroll 4
        for (int k = 0; k < 128; k++) a += spool[k] * Wm1[k * 64 + j];
        z1[j] = lrelu(a);
    }
    __syncthreads();
    if (threadIdx.x < 32) {
        int j = threadIdx.x;
        float a = bm2[j];
        #pragma unroll 4
        for (int k = 0; k < 64; k++) a += z1[k] * Wm2[k * 32 + j];
        z2[j] = lrelu(a);
    }
    __syncthreads();
    if (threadIdx.x == 0) {
        float a = bm3[0];
        #pragma unroll
        for (int k = 0; k < 32; k++) a += z2[k] * Wm3[k];
        out[0] = a;
    }
}

// ---------- launch ----------
extern "C" void kernel_launch(void* const* d_in, const int* in_sizes, int n_in,
                              void* d_out, int out_size, void* d_ws, size_t ws_size,
                              hipStream_t stream)
{
    const float* x        = (const float*)d_in[0];
    const float* fake_pos = (const float*)d_in[1];
    const int*   edge     = (const int*)d_in[2];
    const float* pinf     = (const float*)d_in[3];
    const int*   macro    = (const int*)d_in[4];
    const float* W1    = (const float*)d_in[5];
    const float* b1    = (const float*)d_in[6];
    const float* Wpin  = (const float*)d_in[7];
    const float* att   = (const float*)d_in[8];
    const float* Wpost = (const float*)d_in[9];
    const float* bpost = (const float*)d_in[10];
    const float* Wm1   = (const float*)d_in[11];
    const float* bm1   = (const float*)d_in[12];
    const float* Wm2   = (const float*)d_in[13];
    const float* bm2   = (const float*)d_in[14];
    const float* Wm3   = (const float*)d_in[15];
    const float* bm3   = (const float*)d_in[16];
    float* out = (float*)d_out;

    float* ws = (float*)d_ws;
    // layout (4-byte units); zero region = [0, 1,100,128)
    float*    ismacro = ws;                         //   200,000
    float*    sum_all = ws + 200000;                //        64
    float*    sum_mac = ws + 200064;                //        64
    int*      mcount  = (int*)(ws + 200128);        //   200,000
    int*      cnt     = (int*)(ws + 400128);        //   300,000
    float*    pfsum   = ws + 700128;                //   400,000 (he pinf sums, float4)
    // end zero region (1,100,128)
    int*      row_ptr  = (int*)(ws + 1100128);      //   300,001
    int*      partials = (int*)(ws + 1400132);      //       300
    float*    va       = ws + 1400432;              //        40
    int*      csr      = (int*)(ws + 1400472);      // 2,000,000
    float*    e_att    = ws + 3400472;              //   100,000
    float*    xn_att   = ws + 3500472;              //   200,000
    float*    h        = ws + 3700472;              // 6,400,000 (200k x 32)
    unsigned short* e_feat = (unsigned short*)(ws + 10100472); // 6,400,000 ushorts (3.2M units)
    // total: 13,300,472 units ~= 53.2 MB

    const int* nidx = edge;
    const int* hidx = edge + NNZ;

    fill_f32<<<1024, 256, 0, stream>>>(ws, 1100128LL, 0.f);
    k_ismacro<<<2, 256, 0, stream>>>(macro, ismacro, mcount);
    k_count<<<2048, 256, 0, stream>>>(nidx, hidx, pinf, cnt, pfsum);
    k_va<<<1, 64, 0, stream>>>(W1, b1, att, va);
    k_h<<<2048, 256, 0, stream>>>(x, fake_pos, ismacro, va, h, xn_att);
    k_scan1<<<NB_SCAN, 256, 0, stream>>>(cnt, row_ptr, partials);
    k_scan2<<<1, 512, 0, stream>>>(partials);
    k_scan3<<<NB_SCAN, 256, 0, stream>>>(row_ptr, partials);
    k_scatter<<<2048, 256, 0, stream>>>(nidx, hidx, row_ptr, cnt, csr);
    k_he_agg<<<2048, 256, 0, stream>>>(row_ptr, csr, pfsum, W1, Wpin, b1, att, h, e_feat, e_att);
    k_fused<<<1024, 256, 0, stream>>>(row_ptr, csr, xn_att, e_att, e_feat, Wpost, bpost,
                                      mcount, sum_all, sum_mac);
    k_final<<<1, 256, 0, stream>>>(sum_all, sum_mac, Wm1, bm1, Wm2, bm2, Wm3, bm3, out);
}

// Round 6
// 617.622 us; speedup vs baseline: 1.3802x; 1.3802x over previous
//
#include <hip/hip_runtime.h>
#include <math.h>

#define N_NODES 200000
#define N_HE    100000
#define NNZ     1000000
#define F_RAW   29
#define N_MACRO 512
#define SLOPE   0.1f
#define L_TOTAL (N_NODES + N_HE)   // 300000 combined counters
#define NB_SCAN 293                // ceil(300000/1024)

__device__ __forceinline__ float lrelu(float v) { return v >= 0.f ? v : SLOPE * v; }
__device__ __forceinline__ float bf2f(unsigned short u) { return __uint_as_float(((unsigned)u) << 16); }
__device__ __forceinline__ unsigned short f2bf(float f) {
    unsigned u = __float_as_uint(f);
    unsigned r = u + 0x7FFFu + ((u >> 16) & 1u);   // RNE
    return (unsigned short)(r >> 16);
}

// ---------- fills ----------
__global__ __launch_bounds__(256) void fill_f32(float* p, long long n, float v) {
    long long i = (long long)blockIdx.x * blockDim.x + threadIdx.x;
    long long st = (long long)gridDim.x * blockDim.x;
    for (; i < n; i += st) p[i] = v;
}

__global__ __launch_bounds__(256) void k_ismacro(const int* __restrict__ mi,
                                                 float* __restrict__ ismacro, int* __restrict__ mcount) {
    int i = blockIdx.x * blockDim.x + threadIdx.x;
    if (i < N_MACRO) {
        ismacro[mi[i]] = 1.0f;
        atomicAdd(&mcount[mi[i]], 1);
    }
}

// ---------- va[k] = W1[k,:]·att[:64], va[32] = b1·att[:64] ----------
__global__ __launch_bounds__(64) void k_va(const float* __restrict__ W1, const float* __restrict__ b1,
                                           const float* __restrict__ att, float* __restrict__ va) {
    int t = threadIdx.x;
    if (t < 32) {
        float a = 0.f;
        for (int c = 0; c < 64; c++) a += W1[t * 64 + c] * att[c];
        va[t] = a;
    } else if (t == 32) {
        float a = 0.f;
        for (int c = 0; c < 64; c++) a += b1[c] * att[c];
        va[32] = a;
    }
}

// ---------- build h rows (32 bf16) + xn_att ----------
__global__ __launch_bounds__(256) void k_h(
    const float* __restrict__ x, const float* __restrict__ fp,
    const float* __restrict__ ismacro, const float* __restrict__ va,
    unsigned short* __restrict__ h, float* __restrict__ xn_att)
{
    const int lane = threadIdx.x & 63;
    const int half = lane >> 5, k = lane & 31;
    int wid = (blockIdx.x * blockDim.x + threadIdx.x) >> 6;
    int nw = (gridDim.x * blockDim.x) >> 6;
    float vak = va[k];
    float c0 = va[32];
    for (int base = wid * 2; base < N_NODES; base += nw * 2) {
        int n = base + half;
        float v;
        if (k < 29)       v = x[(size_t)n * F_RAW + k];
        else if (k == 29) v = fp[2 * n];
        else if (k == 30) v = fp[2 * n + 1];
        else              v = ismacro[n];
        h[(size_t)n * 32 + k] = f2bf(v);
        float r = v * vak;
        #pragma unroll
        for (int o = 16; o > 0; o >>= 1) r += __shfl_xor(r, o, 32);
        if (k == 0) xn_att[n] = r + c0;
    }
}

// ---------- counts + per-pin ranks (atomicAdd old value) ----------
__global__ __launch_bounds__(256) void k_count(
    const int* __restrict__ nidx, const int* __restrict__ hidx,
    int* __restrict__ cnt, int* __restrict__ rank_n, int* __restrict__ rank_e)
{
    int i = blockIdx.x * blockDim.x + threadIdx.x;
    int st = gridDim.x * blockDim.x;
    for (int p = i; p < NNZ; p += st) {
        rank_n[p] = atomicAdd(&cnt[nidx[p]], 1);
        rank_e[p] = atomicAdd(&cnt[N_NODES + hidx[p]], 1);
    }
}

// ---------- scan of cnt (length L_TOTAL) -> row_ptr ----------
__global__ __launch_bounds__(256) void k_scan1(const int* __restrict__ cnt,
                                               int* __restrict__ row_ptr, int* __restrict__ partials)
{
    __shared__ int sA[256], sB[256];
    const int t = threadIdx.x;
    const int base = blockIdx.x * 1024 + t * 4;
    int v0 = base + 0 < L_TOTAL ? cnt[base + 0] : 0;
    int v1 = base + 1 < L_TOTAL ? cnt[base + 1] : 0;
    int v2 = base + 2 < L_TOTAL ? cnt[base + 2] : 0;
    int v3 = base + 3 < L_TOTAL ? cnt[base + 3] : 0;
    sA[t] = v0 + v1 + v2 + v3;
    __syncthreads();
    int* src = sA; int* dst = sB;
    for (int off = 1; off < 256; off <<= 1) {
        int v = src[t];
        if (t >= off) v += src[t - off];
        dst[t] = v;
        __syncthreads();
        int* tmp = src; src = dst; dst = tmp;
    }
    int excl = t > 0 ? src[t - 1] : 0;
    if (base + 0 < L_TOTAL) row_ptr[base + 0] = excl;
    if (base + 1 < L_TOTAL) row_ptr[base + 1] = excl + v0;
    if (base + 2 < L_TOTAL) row_ptr[base + 2] = excl + v0 + v1;
    if (base + 3 < L_TOTAL) row_ptr[base + 3] = excl + v0 + v1 + v2;
    if (t == 255) partials[blockIdx.x] = src[255];
}

__global__ __launch_bounds__(512) void k_scan2(int* __restrict__ partials)
{
    __shared__ int sA[512], sB[512];
    const int t = threadIdx.x;
    sA[t] = t < NB_SCAN ? partials[t] : 0;
    __syncthreads();
    int* src = sA; int* dst = sB;
    for (int off = 1; off < 512; off <<= 1) {
        int v = src[t];
        if (t >= off) v += src[t - off];
        dst[t] = v;
        __syncthreads();
        int* tmp = src; src = dst; dst = tmp;
    }
    if (t < NB_SCAN) partials[t] = t > 0 ? src[t - 1] : 0;
    if (t == 0) partials[NB_SCAN] = src[511];
}

__global__ __launch_bounds__(256) void k_scan3(int* __restrict__ row_ptr, const int* __restrict__ partials)
{
    const int base = blockIdx.x * 1024 + threadIdx.x * 4;
    int add = partials[blockIdx.x];
    #pragma unroll
    for (int k = 0; k < 4; k++)
        if (base + k < L_TOTAL) row_ptr[base + k] += add;
    if (blockIdx.x == 0 && threadIdx.x == 0) row_ptr[L_TOTAL] = partials[NB_SCAN];
}

// ---------- atomic-free scatter: csr + pinf into he-slot order ----------
__global__ __launch_bounds__(256) void k_scatter(
    const int* __restrict__ nidx, const int* __restrict__ hidx,
    const int* __restrict__ row_ptr,
    const int* __restrict__ rank_n, const int* __restrict__ rank_e,
    const float4* __restrict__ pf4, int* __restrict__ csr, float4* __restrict__ pf_he)
{
    int i = blockIdx.x * blockDim.x + threadIdx.x;
    int st = gridDim.x * blockDim.x;
    for (int p = i; p < NNZ; p += st) {
        int n = nidx[p], e = hidx[p];
        csr[row_ptr[n] + rank_n[p]] = e;
        int pe = row_ptr[N_NODES + e] + rank_e[p];  // absolute slot (>= NNZ)
        csr[pe] = n;
        pf_he[pe - NNZ] = pf4[p];
    }
}

// ---------- he-side: gather bf16 h rows + coalesced pinf, matvec W1 ----------
__global__ __launch_bounds__(256) void k_he_agg(
    const int* __restrict__ row_ptr, const int* __restrict__ csr,
    const float* __restrict__ pf_he,
    const float* __restrict__ W1, const float* __restrict__ Wpin,
    const float* __restrict__ b1, const float* __restrict__ att,
    const unsigned short* __restrict__ h,
    unsigned short* __restrict__ e_feat, float* __restrict__ e_att)
{
    __shared__ float sW1[32 * 64];
    __shared__ float sWp[4 * 64];
    __shared__ float sb1[64];
    for (int i = threadIdx.x; i < 32 * 64; i += 256) sW1[i] = W1[i];
    for (int i = threadIdx.x; i < 4 * 64; i += 256) sWp[i] = Wpin[i];
    if (threadIdx.x < 64) sb1[threadIdx.x] = b1[threadIdx.x];
    __syncthreads();
    const int lane = threadIdx.x & 63;
    const int half = lane >> 5, k32 = lane & 31;
    float att2 = att[64 + lane];
    int wid = (blockIdx.x * blockDim.x + threadIdx.x) >> 6;
    int nw = (gridDim.x * blockDim.x) >> 6;
    for (int e = wid; e < N_HE; e += nw) {
        int start = row_ptr[N_NODES + e];
        int deg = row_ptr[N_NODES + e + 1] - start;
        // gather h rows: each half-wave loads one 64B bf16 row per step
        float hs = 0.f;
        for (int t0 = 0; t0 < deg; t0 += 8) {
            #pragma unroll
            for (int r = 0; r < 4; r++) {
                int t = t0 + 2 * r + half;
                if (t < deg) {
                    int n = csr[start + t];
                    hs += bf2f(h[(size_t)n * 32 + k32]);
                }
            }
        }
        hs += __shfl_xor(hs, 32, 64);
        // coalesced pinf sum from pf_he
        float pv = 0.f;
        const float* pf = pf_he + 4 * (size_t)(start - NNZ);
        for (int i4 = lane; i4 < 4 * deg; i4 += 64) pv += pf[i4];
        pv += __shfl_xor(pv, 4);  pv += __shfl_xor(pv, 8);
        pv += __shfl_xor(pv, 16); pv += __shfl_xor(pv, 32);
        float p0 = __shfl(pv, 0, 64), p1 = __shfl(pv, 1, 64);
        float p2 = __shfl(pv, 2, 64), p3 = __shfl(pv, 3, 64);
        float acc = (float)deg * sb1[lane]
                  + p0 * sWp[lane] + p1 * sWp[64 + lane]
                  + p2 * sWp[128 + lane] + p3 * sWp[192 + lane];
        #pragma unroll
        for (int kk = 0; kk < 32; kk++) acc += __shfl(hs, kk, 64) * sW1[kk * 64 + lane];
        float d = (float)(deg > 0 ? deg : 1);
        float v = acc / d;
        e_feat[(size_t)e * 64 + lane] = f2bf(v);
        float r = v * att2;
        #pragma unroll
        for (int o = 32; o > 0; o >>= 1) r += __shfl_down(r, o, 64);
        if (lane == 0) e_att[e] = r;
    }
}

// ---------- fused softmax+PNA + register-W GEMM + lrelu + pools ----------
__global__ __launch_bounds__(256, 4) void k_fused(
    const int* __restrict__ row_ptr, const int* __restrict__ csr,
    const float* __restrict__ xn_att, const float* __restrict__ e_att,
    const unsigned short* __restrict__ e_feat,
    const float* __restrict__ Wpost, const float* __restrict__ bpost,
    const int* __restrict__ mcount,
    float* __restrict__ sum_all, float* __restrict__ sum_mac)
{
    __shared__ __align__(16) float scat[32 * 288];   // 32 nodes x 8 blocks x 36 words
    const int lane = threadIdx.x & 63;
    const int wave = threadIdx.x >> 6;
    const int kg = lane >> 3;
    const int cg = lane & 7;
    float2 wreg[32];
    {
        const float2* W2 = (const float2*)Wpost;
        #pragma unroll
        for (int t = 0; t < 32; t++)
            wreg[t] = W2[(size_t)(32 * kg + t) * 32 + wave * 8 + cg];
    }
    float2 bias = ((const float2*)bpost)[wave * 8 + cg];
    float2 pool = make_float2(0.f, 0.f), pmac = make_float2(0.f, 0.f);
    const int off_c = 36 * (lane >> 5) + (lane & 31);
    const int nbatches = N_NODES / 32;  // 6250
    for (int b = blockIdx.x; b < nbatches; b += gridDim.x) {
        const int base = b * 32;
        __syncthreads();
        for (int i = 0; i < 8; i++) {
            int j = wave * 8 + i;
            int n = base + j;
            int start = row_ptr[n];
            int deg = row_ptr[n + 1] - start;
            float xn = xn_att[n];
            float sw = 0.f, s = 0.f, sq = 0.f, mx = -INFINITY, mn = INFINITY;
            int t = 0;
            for (; t + 4 <= deg; t += 4) {
                int e0 = csr[start + t],     e1 = csr[start + t + 1];
                int e2 = csr[start + t + 2], e3 = csr[start + t + 3];
                float w0 = __expf(lrelu(xn + e_att[e0]));
                float w1 = __expf(lrelu(xn + e_att[e1]));
                float w2 = __expf(lrelu(xn + e_att[e2]));
                float w3 = __expf(lrelu(xn + e_att[e3]));
                float v0 = bf2f(e_feat[(size_t)e0 * 64 + lane]) * w0;
                float v1 = bf2f(e_feat[(size_t)e1 * 64 + lane]) * w1;
                float v2 = bf2f(e_feat[(size_t)e2 * 64 + lane]) * w2;
                float v3 = bf2f(e_feat[(size_t)e3 * 64 + lane]) * w3;
                sw += w0 + w1 + w2 + w3;
                s  += v0 + v1 + v2 + v3;
                sq += v0 * v0 + v1 * v1 + v2 * v2 + v3 * v3;
                mx = fmaxf(fmaxf(mx, v0), fmaxf(fmaxf(v1, v2), v3));
                mn = fminf(fminf(mn, v0), fminf(fminf(v1, v2), v3));
            }
            for (; t < deg; t++) {
                int e = csr[start + t];
                float w = __expf(lrelu(xn + e_att[e]));
                float v = bf2f(e_feat[(size_t)e * 64 + lane]) * w;
                sw += w; s += v; sq += v * v;
                mx = fmaxf(mx, v); mn = fminf(mn, v);
            }
            float invD = 1.f / (sw + 1e-16f);
            float dc = (float)(deg > 0 ? deg : 1);
            float mean = s * invD / dc;
            float sqm  = sq * invD * invD / dc;
            float stdv = sqrtf(fmaxf(sqm - mean * mean, 0.f) + 1e-12f);
            float* row = &scat[j * 288];
            row[off_c]       = mean;
            row[72 + off_c]  = deg > 0 ? mx * invD : 0.f;
            row[144 + off_c] = deg > 0 ? mn * invD : 0.f;
            row[216 + off_c] = stdv;
        }
        __syncthreads();
        for (int j = 0; j < 32; j++) {
            const float4* sc = (const float4*)&scat[j * 288 + kg * 36];
            float2 a = make_float2(0.f, 0.f);
            #pragma unroll
            for (int i = 0; i < 8; i++) {
                float4 c4 = sc[i];
                a.x += c4.x * wreg[4 * i + 0].x + c4.y * wreg[4 * i + 1].x
                     + c4.z * wreg[4 * i + 2].x + c4.w * wreg[4 * i + 3].x;
                a.y += c4.x * wreg[4 * i + 0].y + c4.y * wreg[4 * i + 1].y
                     + c4.z * wreg[4 * i + 2].y + c4.w * wreg[4 * i + 3].y;
            }
            a.x += __shfl_xor(a.x, 8);  a.y += __shfl_xor(a.y, 8);
            a.x += __shfl_xor(a.x, 16); a.y += __shfl_xor(a.y, 16);
            a.x += __shfl_xor(a.x, 32); a.y += __shfl_xor(a.y, 32);
            if (kg == 0) {
                float h0 = lrelu(a.x + bias.x);
                float h1 = lrelu(a.y + bias.y);
                float mc = (float)mcount[base + j];
                pool.x += h0; pool.y += h1;
                pmac.x += mc * h0; pmac.y += mc * h1;
            }
        }
    }
    if (kg == 0) {
        int c0 = wave * 16 + 2 * cg;
        atomicAdd(&sum_all[c0],     pool.x);
        atomicAdd(&sum_all[c0 + 1], pool.y);
        atomicAdd(&sum_mac[c0],     pmac.x);
        atomicAdd(&sum_mac[c0 + 1], pmac.y);
    }
}

// ---------- tiny MLP head ----------
__global__ __launch_bounds__(256) void k_final(
    const float* __restrict__ sum_all, const float* __restrict__ sum_mac,
    const float* __restrict__ Wm1, const float* __restrict__ bm1,
    const float* __restrict__ Wm2, const float* __restrict__ bm2,
    const float* __restrict__ Wm3, const float* __restrict__ bm3,
    float* __restrict__ out)
{
    __shared__ float spool[128];
    __shared__ float z1[64];
    __shared__ float z2[32];
    if (threadIdx.x < 64) {
        spool[threadIdx.x]      = sum_mac[threadIdx.x] / (float)N_MACRO;
        spool[64 + threadIdx.x] = sum_all[threadIdx.x] / (float)N_NODES;
    }
    __syncthreads();
    if (threadIdx.x < 64) {
        int j = threadIdx.x;
        float a = bm1[j];
        #pragma unroll 4
        for (int k = 0; k < 128; k++) a += spool[k] * Wm1[k * 64 + j];
        z1[j] = lrelu(a);
    }
    __syncthreads();
    if (threadIdx.x < 32) {
        int j = threadIdx.x;
        float a = bm2[j];
        #pragma unroll 4
        for (int k = 0; k < 64; k++) a += z1[k] * Wm2[k * 32 + j];
        z2[j] = lrelu(a);
    }
    __syncthreads();
    if (threadIdx.x == 0) {
        float a = bm3[0];
        #pragma unroll
        for (int k = 0; k < 32; k++) a += z2[k] * Wm3[k];
        out[0] = a;
    }
}

// ---------- launch ----------
extern "C" void kernel_launch(void* const* d_in, const int* in_sizes, int n_in,
                              void* d_out, int out_size, void* d_ws, size_t ws_size,
                              hipStream_t stream)
{
    const float* x        = (const float*)d_in[0];
    const float* fake_pos = (const float*)d_in[1];
    const int*   edge     = (const int*)d_in[2];
    const float* pinf     = (const float*)d_in[3];
    const int*   macro    = (const int*)d_in[4];
    const float* W1    = (const float*)d_in[5];
    const float* b1    = (const float*)d_in[6];
    const float* Wpin  = (const float*)d_in[7];
    const float* att   = (const float*)d_in[8];
    const float* Wpost = (const float*)d_in[9];
    const float* bpost = (const float*)d_in[10];
    const float* Wm1   = (const float*)d_in[11];
    const float* bm1   = (const float*)d_in[12];
    const float* Wm2   = (const float*)d_in[13];
    const float* bm2   = (const float*)d_in[14];
    const float* Wm3   = (const float*)d_in[15];
    const float* bm3   = (const float*)d_in[16];
    float* out = (float*)d_out;

    float* ws = (float*)d_ws;
    // layout (4-byte units); zero region = [0, 700128)
    float*    ismacro = ws;                         //   200,000
    float*    sum_all = ws + 200000;                //        64
    float*    sum_mac = ws + 200064;                //        64
    int*      mcount  = (int*)(ws + 200128);        //   200,000
    int*      cnt     = (int*)(ws + 400128);        //   300,000
    // end zero region (700,128)
    int*      row_ptr  = (int*)(ws + 700128);       //   300,001
    int*      partials = (int*)(ws + 1000132);      //       300
    float*    va       = ws + 1000432;              //        40
    int*      rank_n   = (int*)(ws + 1000472);      // 1,000,000
    int*      rank_e   = (int*)(ws + 2000472);      // 1,000,000
    int*      csr      = (int*)(ws + 3000472);      // 2,000,000
    float*    pf_he    = ws + 5000472;              // 4,000,000 (16B-aligned: 5000472%4==0)
    float*    e_att    = ws + 9000472;              //   100,000
    float*    xn_att   = ws + 9100472;              //   200,000
    unsigned short* h      = (unsigned short*)(ws + 9300472);  // 6.4M ushort (3.2M units)
    unsigned short* e_feat = (unsigned short*)(ws + 12500472); // 6.4M ushort (3.2M units)
    // total: 15,700,472 units ~= 62.8 MB

    const int* nidx = edge;
    const int* hidx = edge + NNZ;

    fill_f32<<<1024, 256, 0, stream>>>(ws, 700128LL, 0.f);
    k_ismacro<<<2, 256, 0, stream>>>(macro, ismacro, mcount);
    k_count<<<2048, 256, 0, stream>>>(nidx, hidx, cnt, rank_n, rank_e);
    k_va<<<1, 64, 0, stream>>>(W1, b1, att, va);
    k_h<<<2048, 256, 0, stream>>>(x, fake_pos, ismacro, va, h, xn_att);
    k_scan1<<<NB_SCAN, 256, 0, stream>>>(cnt, row_ptr, partials);
    k_scan2<<<1, 512, 0, stream>>>(partials);
    k_scan3<<<NB_SCAN, 256, 0, stream>>>(row_ptr, partials);
    k_scatter<<<2048, 256, 0, stream>>>(nidx, hidx, row_ptr, rank_n, rank_e,
                                        (const float4*)pinf, csr, (float4*)pf_he);
    k_he_agg<<<2048, 256, 0, stream>>>(row_ptr, csr, pf_he, W1, Wpin, b1, att, h, e_feat, e_att);
    k_fused<<<1024, 256, 0, stream>>>(row_ptr, csr, xn_att, e_att, e_feat, Wpost, bpost,
                                      mcount, sum_all, sum_mac);
    k_final<<<1, 256, 0, stream>>>(sum_all, sum_mac, Wm1, bm1, Wm2, bm2, Wm3, bm3, out);
}